// Round 1
// baseline (125.716 us; speedup 1.0000x reference)
//
#include <hip/hip_runtime.h>

// Problem constants (fixed by the reference):
//   B = 4194304 patches, each 2x2 f32  -> one float4 per patch
//   L = 5 affine-tanh layers, THRESHOLD = 0
#define B_TOTAL 4194304
#define NLAYER  5
#define NP      8      // patches per thread
#define BLOCK   256

__device__ __forceinline__ float fast_sigmoid(float z) {
    // 1/(1+exp(-z)); __expf -> v_exp_f32. Safe at extremes: exp(+inf)=inf -> 0, exp(-inf)=0 -> 1.
    return 1.0f / (1.0f + __expf(-z));
}

__device__ __forceinline__ float fast_tanh(float z) {
    // 1 - 2/(exp(2z)+1). Safe: z->+inf gives 1-0=1; z->-inf gives 1-2=-1. No inf/inf NaN.
    float t = __expf(2.0f * z);
    return 1.0f - 2.0f / (t + 1.0f);
}

__global__ __launch_bounds__(BLOCK) void fraud_kernel(
    const float4* __restrict__ data,   // [B] patches as float4
    const float*  __restrict__ Wc,     // [4]
    const float*  __restrict__ bc,     // [1]
    const float*  __restrict__ Wl,     // [L*4]
    const float*  __restrict__ bl,     // [L*2]
    const float*  __restrict__ scale,  // [L*2]
    const float*  __restrict__ shift,  // [L*2]
    const float*  __restrict__ Wf,     // [2]
    const float*  __restrict__ bf,     // [1]
    float*        __restrict__ out)    // [B]
{
    // ---- Load all weights into registers (wave-uniform, L1-resident) ----
    const float4 wc = *(const float4*)Wc;
    const float  bcv = bc[0];

    float w[NLAYER][4], bb[NLAYER][2], sc[NLAYER][2], sh[NLAYER][2];
#pragma unroll
    for (int l = 0; l < NLAYER; ++l) {
        float4 wl = *(const float4*)(Wl + 4 * l);
        w[l][0] = wl.x; w[l][1] = wl.y; w[l][2] = wl.z; w[l][3] = wl.w;
        float2 b2 = *(const float2*)(bl + 2 * l);
        bb[l][0] = b2.x; bb[l][1] = b2.y;
        float2 s2 = *(const float2*)(scale + 2 * l);
        sc[l][0] = s2.x; sc[l][1] = s2.y;
        float2 h2 = *(const float2*)(shift + 2 * l);
        sh[l][0] = h2.x; sh[l][1] = h2.y;
    }
    const float2 wf = *(const float2*)Wf;
    const float  bfv = bf[0];

    const int tid    = blockIdx.x * BLOCK + threadIdx.x;
    const int stride = gridDim.x * BLOCK;

#pragma unroll
    for (int k = 0; k < NP; ++k) {
        const int i = tid + k * stride;    // coalesced across the wave
        const float4 d = data[i];

        // Conv2d(1,1,2) on 2x2 patch == dot4 + bias, then sigmoid
        float z = d.x * wc.x + d.y * wc.y + d.z * wc.z + d.w * wc.w + bcv;
        float x0 = fast_sigmoid(z);
        float x1 = 0.0f;

#pragma unroll
        for (int l = 0; l < NLAYER; ++l) {
            // x @ W.T + b  (W is [2,2], row-major)
            float y0 = fast_tanh(x0 * w[l][0] + x1 * w[l][1] + bb[l][0]) * sc[l][0] + sh[l][0];
            float y1 = fast_tanh(x0 * w[l][2] + x1 * w[l][3] + bb[l][1]) * sc[l][1] + sh[l][1];
            x0 = y0; x1 = y1;
        }

        out[i] = x0 * wf.x + x1 * wf.y + bfv;
    }
}

extern "C" void kernel_launch(void* const* d_in, const int* in_sizes, int n_in,
                              void* d_out, int out_size, void* d_ws, size_t ws_size,
                              hipStream_t stream) {
    const float4* data  = (const float4*)d_in[0];
    const float*  Wc    = (const float*)d_in[1];
    const float*  bc    = (const float*)d_in[2];
    const float*  Wl    = (const float*)d_in[3];
    const float*  bl    = (const float*)d_in[4];
    const float*  scale = (const float*)d_in[5];
    const float*  shift = (const float*)d_in[6];
    const float*  Wf    = (const float*)d_in[7];
    const float*  bf    = (const float*)d_in[8];
    float* out = (float*)d_out;

    const int grid = B_TOTAL / (BLOCK * NP);   // 4194304 / 2048 = 2048 blocks
    fraud_kernel<<<grid, BLOCK, 0, stream>>>(data, Wc, bc, Wl, bl, scale, shift, Wf, bf, out);
}